// Round 5
// baseline (217.654 us; speedup 1.0000x reference)
//
#include <hip/hip_runtime.h>

// ---------------------------------------------------------------------------
// TrimMultiheadAttention: fused in-proj (x@W^T+b), causal linear attention
// (chunked scan over outer-product state), out-proj, [T,B,E] output.
// All matmuls FP16 MFMA 16x16x32, fp32 accumulate.
// R5: 256x256 GEMM tile, 8 waves (512 thr), 2-phase dbuf + counted vmcnt(8),
//     T2 XOR swizzle (kept), bijective chunked XCD swizzle (T1).
//     R4 post-mortem: conflicts=0 but latency-bound at 128^2 (4 MFMA/KB);
//     256^2 gives 8 MFMA/KB + 1 block-generation instead of 3.
//
// Shapes: T=2048, B=2, E=1024, H=16, D=64.  TOK = B*T = 4096.
//
// Workspace layout (bytes), peak 64 MB:
//   [0,8M)    WB   : fp16 weights Wq|Wk|Wv|Wo (1Mi elems each)
//   [8,16M)   XQ   : fp16 [4096][1024] packed query  (later reused as ATTN)
//   [16,24M)  XK   :                  key            (later reused as GT)
//   [24,32M)  XV   :                  value          (later reused as ST)
//   [32,40M)  Q    : fp16 [4096][1024]
//   [40,48M)  K    : fp16 [4096][1024]
//   [48,56M)  KT   : fp16 [1024][4096]  (K transposed)
//   [56,64M)  VT   : fp16 [1024][4096]  (V transposed)
// ---------------------------------------------------------------------------

#define TSEQ 2048
#define BBATCH 2
#define EE 1024
#define TOK 4096
#define NCH 32

typedef _Float16 half8 __attribute__((ext_vector_type(8)));
typedef _Float16 half4 __attribute__((ext_vector_type(4)));
typedef float f32x4 __attribute__((ext_vector_type(4)));

#ifndef __has_builtin
#define __has_builtin(x) 0
#endif
#if __has_builtin(__builtin_amdgcn_global_load_lds)
#define USE_GLL 1
#endif

#ifdef USE_GLL
typedef __attribute__((address_space(1))) const unsigned int guint_t;
typedef __attribute__((address_space(3))) unsigned int luint_t;
#endif

// ---------------- pack kernels: fp32 -> fp16, [T,B,E] -> [b*T+t][E] ----------
__global__ __launch_bounds__(256) void pack_x_kernel(
    const float* __restrict__ q, const float* __restrict__ k,
    const float* __restrict__ v,
    _Float16* __restrict__ xq, _Float16* __restrict__ xk,
    _Float16* __restrict__ xv) {
  const int blk = blockIdx.x;
  const int m = blk >> 12;        // 0=q 1=k 2=v
  const int row = blk & 4095;     // token = b*TSEQ + t
  const int b = row >> 11, t = row & 2047;
  const float* src = (m == 0 ? q : (m == 1 ? k : v)) +
                     (size_t)t * (BBATCH * EE) + (size_t)b * EE;
  _Float16* dst = (m == 0 ? xq : (m == 1 ? xk : xv)) + (size_t)row * EE;
  const int e = threadIdx.x * 4;
  f32x4 f = *(const f32x4*)&src[e];
  half4 h;
  h[0] = (_Float16)f[0]; h[1] = (_Float16)f[1];
  h[2] = (_Float16)f[2]; h[3] = (_Float16)f[3];
  *(half4*)&dst[e] = h;
}

__global__ __launch_bounds__(256) void pack_w_kernel(
    const float* __restrict__ wq, const float* __restrict__ wk,
    const float* __restrict__ wv, const float* __restrict__ wo,
    _Float16* __restrict__ wb) {
  const int blk = blockIdx.x;
  const int m = blk >> 10, row = blk & 1023;
  const float* src =
      (m == 0 ? wq : (m == 1 ? wk : (m == 2 ? wv : wo))) + (size_t)row * EE;
  _Float16* dst = wb + (size_t)m * EE * EE + (size_t)row * EE;
  const int e = threadIdx.x * 4;
  f32x4 f = *(const f32x4*)&src[e];
  half4 h;
  h[0] = (_Float16)f[0]; h[1] = (_Float16)f[1];
  h[2] = (_Float16)f[2]; h[3] = (_Float16)f[3];
  *(half4*)&dst[e] = h;
}

// ---------------- 256x256 GEMM core, K=1024, 2-phase dbuf, 8 waves ----------
// LDS logical tile [256 rows][8 slots of 16B]; element (r,s) at slot s^(r&7).
// Stage keeps LDS dest LINEAR (global_load_lds requirement) and swizzles the
// global SOURCE column (rule #21: both sides same involution).
__device__ __forceinline__ void stage256(
    const _Float16* __restrict__ A, const _Float16* __restrict__ Bm,
    long arow0, long brow0, int k0, int tid, int w,
    _Float16* __restrict__ Ab, _Float16* __restrict__ Bb) {
#pragma unroll
  for (int i = 0; i < 4; ++i) {
    const int flat = i * 512 + tid;  // 16B units, 0..2047
    const int r = flat >> 3, s = flat & 7;
    const int c = (s ^ (r & 7)) * 8;  // swizzled source column (elems)
    const _Float16* ga = &A[(size_t)(arow0 + r) * 1024 + k0 + c];
    const _Float16* gb = &Bm[(size_t)(brow0 + r) * 1024 + k0 + c];
#ifdef USE_GLL
    const int ubase = (i * 512 + w * 64) * 8;  // wave-uniform elem offset
    __builtin_amdgcn_global_load_lds((guint_t*)ga, (luint_t*)&Ab[ubase], 16, 0,
                                     0);
    __builtin_amdgcn_global_load_lds((guint_t*)gb, (luint_t*)&Bb[ubase], 16, 0,
                                     0);
#else
    *(half8*)&Ab[flat * 8] = *(const half8*)ga;
    *(half8*)&Bb[flat * 8] = *(const half8*)gb;
#endif
  }
}

// 8 waves as 2(M) x 4(N); per-wave output 128x64 = acc[8][4] fragments.
__device__ __forceinline__ void gemm_core256(
    const _Float16* __restrict__ A, const _Float16* __restrict__ Bm,
    long arow0, long brow0, int tid, f32x4 (&acc)[8][4],
    _Float16 (&Ab)[2][16384], _Float16 (&Bb)[2][16384]) {
  const int lane = tid & 63, w = tid >> 6;
  const int wr = w >> 2, wc = w & 3;
  const int l15 = lane & 15, lg = lane >> 4;
  const int swz = l15 & 7;  // row&7 for all fragment rows (others mult of 16)

#ifdef USE_GLL
  stage256(A, Bm, arow0, brow0, 0, tid, w, Ab[0], Bb[0]);
  for (int kt = 0; kt < 16; ++kt) {
    const int cur = kt & 1;
    if (kt < 15) {
      stage256(A, Bm, arow0, brow0, (kt + 1) * 64, tid, w, Ab[cur ^ 1],
               Bb[cur ^ 1]);
      asm volatile("s_waitcnt vmcnt(8)" ::: "memory");  // tile kt arrived
    } else {
      asm volatile("s_waitcnt vmcnt(0)" ::: "memory");
    }
    __builtin_amdgcn_s_barrier();      // all waves' tile-kt loads visible
    asm volatile("" ::: "memory");     // keep ds_reads below the barrier
#pragma unroll
    for (int ks = 0; ks < 2; ++ks) {
      half8 af[8], bf[4];
#pragma unroll
      for (int mi = 0; mi < 8; ++mi)
        af[mi] = *(const half8*)&Ab[cur][(wr * 128 + mi * 16 + l15) * 64 +
                                         ((ks * 4 + lg) ^ swz) * 8];
#pragma unroll
      for (int ni = 0; ni < 4; ++ni)
        bf[ni] = *(const half8*)&Bb[cur][(wc * 64 + ni * 16 + l15) * 64 +
                                         ((ks * 4 + lg) ^ swz) * 8];
#pragma unroll
      for (int mi = 0; mi < 8; ++mi)
#pragma unroll
        for (int ni = 0; ni < 4; ++ni)
          acc[mi][ni] = __builtin_amdgcn_mfma_f32_16x16x32_f16(
              af[mi], bf[ni], acc[mi][ni], 0, 0, 0);
    }
    asm volatile("" ::: "memory");     // keep ds_reads above the barrier
    __builtin_amdgcn_s_barrier();      // safe to overwrite buf[cur] next iter
  }
#else
  for (int kt = 0; kt < 16; ++kt) {
    __syncthreads();
    stage256(A, Bm, arow0, brow0, kt * 64, tid, w, Ab[0], Bb[0]);
    __syncthreads();
#pragma unroll
    for (int ks = 0; ks < 2; ++ks) {
      half8 af[8], bf[4];
#pragma unroll
      for (int mi = 0; mi < 8; ++mi)
        af[mi] = *(const half8*)&Ab[0][(wr * 128 + mi * 16 + l15) * 64 +
                                       ((ks * 4 + lg) ^ swz) * 8];
#pragma unroll
      for (int ni = 0; ni < 4; ++ni)
        bf[ni] = *(const half8*)&Bb[0][(wc * 64 + ni * 16 + l15) * 64 +
                                       ((ks * 4 + lg) ^ swz) * 8];
#pragma unroll
      for (int mi = 0; mi < 8; ++mi)
#pragma unroll
        for (int ni = 0; ni < 4; ++ni)
          acc[mi][ni] = __builtin_amdgcn_mfma_f32_16x16x32_f16(
              af[mi], bf[ni], acc[mi][ni], 0, 0, 0);
    }
  }
#endif
}

// ---------------- merged in-projection GEMM (192 blocks, XCD-chunked) -------
// 16 m-blocks (tokens) x 12 cols (3 sections x 4 n-blocks).  Each XCD owns a
// 4x6 rectangle: A-band ~2MB + B-cols ~3MB stay L2-resident.
__global__ __launch_bounds__(512, 1) void gemm_inproj(
    const _Float16* __restrict__ X, const _Float16* __restrict__ WB,
    const float* __restrict__ bias, _Float16* __restrict__ Qb,
    _Float16* __restrict__ Kbf, _Float16* __restrict__ KT,
    _Float16* __restrict__ VT) {
  __shared__ __align__(16) _Float16 Ab[2][16384];
  __shared__ __align__(16) _Float16 Bb[2][16384];
  const int tid = threadIdx.x;
  const int bid = blockIdx.x;          // 0..191
  const int xcd = bid & 7, cid = bid >> 3;   // consecutive ids round-robin XCDs
  const int rr = xcd >> 1, rc = xcd & 1;     // 4x2 grid of 4x6 rectangles
  const int mb = rr * 4 + cid / 6;           // 0..15
  const int col = rc * 6 + cid % 6;          // 0..11
  const int which = col >> 2, nb = col & 3;  // section, n-block
  const long arow0 = (long)mb * 256;         // token
  const long brow0 = (long)nb * 256;         // e within section
  const _Float16* A = X + (size_t)which * (TOK * EE);
  const _Float16* Bm = WB + (size_t)which * (EE * EE);
  const float* bs = bias + which * EE;

  f32x4 acc[8][4] = {};
  gemm_core256(A, Bm, arow0, brow0, tid, acc, Ab, Bb);

  const int lane = tid & 63, w = tid >> 6;
  const int wr = w >> 2, wc = w & 3;
  const int l15 = lane & 15, lg = lane >> 4;
#pragma unroll
  for (int mi = 0; mi < 8; ++mi) {
#pragma unroll
    for (int ni = 0; ni < 4; ++ni) {
      const long gm = arow0 + wr * 128 + mi * 16 + lg * 4;  // token (+r)
      const long gn = brow0 + wc * 64 + ni * 16 + l15;      // e in section
      const float bv = bs[gn];
      float vv[4];
#pragma unroll
      for (int r = 0; r < 4; ++r) vv[r] = acc[mi][ni][r] + bv;
      if (which == 0) {
#pragma unroll
        for (int r = 0; r < 4; ++r)
          Qb[(size_t)(gm + r) * EE + gn] = (_Float16)vv[r];
      } else if (which == 1) {
#pragma unroll
        for (int r = 0; r < 4; ++r)
          Kbf[(size_t)(gm + r) * EE + gn] = (_Float16)vv[r];
        half4 pk;
#pragma unroll
        for (int r = 0; r < 4; ++r) pk[r] = (_Float16)vv[r];
        *(half4*)&KT[(size_t)gn * TOK + gm] = pk;
      } else {
        half4 pk;
#pragma unroll
        for (int r = 0; r < 4; ++r) pk[r] = (_Float16)vv[r];
        *(half4*)&VT[(size_t)gn * TOK + gm] = pk;
      }
    }
  }
}

// ---------------- out projection (64 blocks, XCD-chunked) -------------------
// OF[t][b][eo] = Wo[eo][:] . attn[tok][:] + bo[eo].  4 m-blocks(eo) x 16 cols.
__global__ __launch_bounds__(512, 1) void gemm_out(
    const _Float16* __restrict__ Wo, const _Float16* __restrict__ ATT,
    const float* __restrict__ bo, float* __restrict__ OF) {
  __shared__ __align__(16) _Float16 Ab[2][16384];
  __shared__ __align__(16) _Float16 Bb[2][16384];
  const int tid = threadIdx.x;
  const int bid = blockIdx.x;                // 0..63
  const int xcd = bid & 7, cid = bid >> 3;   // 8 per XCD
  const int rr = xcd >> 2, rc = xcd & 3;     // 2x4 grid of 2x4 rectangles
  const int mb = rr * 2 + cid / 4;           // 0..3  (eo)
  const int col = rc * 4 + cid % 4;          // 0..15 (token)
  const long arow0 = (long)mb * 256;
  const long brow0 = (long)col * 256;

  f32x4 acc[8][4] = {};
  gemm_core256(Wo, ATT, arow0, brow0, tid, acc, Ab, Bb);

  const int lane = tid & 63, w = tid >> 6;
  const int wr = w >> 2, wc = w & 3;
  const int l15 = lane & 15, lg = lane >> 4;
#pragma unroll
  for (int mi = 0; mi < 8; ++mi) {
#pragma unroll
    for (int ni = 0; ni < 4; ++ni) {
      const long gm = arow0 + wr * 128 + mi * 16 + lg * 4;  // eo (+r)
      const long gn = brow0 + wc * 64 + ni * 16 + l15;      // token
      const int t = (int)(gn & 2047), b2 = (int)(gn >> 11);
      f32x4 res;
#pragma unroll
      for (int r = 0; r < 4; ++r) res[r] = acc[mi][ni][r] + bo[gm + r];
      *(f32x4*)&OF[(size_t)t * (BBATCH * EE) + (size_t)b2 * EE + gm] = res;
    }
  }
}

// ---------------- K1: per-chunk G^T = (K_c^T V_c)^T stored [d2][d1] ---------
__global__ __launch_bounds__(64) void chunk_g_kernel(
    const _Float16* __restrict__ KT, const _Float16* __restrict__ VT,
    _Float16* __restrict__ GT) {
  const int c = blockIdx.x & 31, bh = blockIdx.x >> 5;
  const int b = bh >> 4, h = bh & 15;
  const int lane = threadIdx.x, l15 = lane & 15, lg = lane >> 4;
  const long tok0 = (long)b * TSEQ + c * 64;

  half8 af[4][2], bf[4][2];
#pragma unroll
  for (int ma = 0; ma < 4; ++ma)
#pragma unroll
    for (int ks = 0; ks < 2; ++ks) {
      const size_t rowoff = (size_t)(h * 64 + ma * 16 + l15) * TOK + tok0 +
                            ks * 32 + lg * 8;
      af[ma][ks] = *(const half8*)&KT[rowoff];
      bf[ma][ks] = *(const half8*)&VT[rowoff];
    }
  f32x4 acc[4][4] = {};
#pragma unroll
  for (int ks = 0; ks < 2; ++ks)
#pragma unroll
    for (int ma = 0; ma < 4; ++ma)
#pragma unroll
      for (int nb = 0; nb < 4; ++nb)
        acc[ma][nb] = __builtin_amdgcn_mfma_f32_16x16x32_f16(
            af[ma][ks], bf[nb][ks], acc[ma][nb], 0, 0, 0);
  _Float16* g = GT + ((size_t)bh * NCH + c) * 4096;
#pragma unroll
  for (int ma = 0; ma < 4; ++ma)
#pragma unroll
    for (int nb = 0; nb < 4; ++nb) {
      half4 pk;
#pragma unroll
      for (int r = 0; r < 4; ++r) pk[r] = (_Float16)acc[ma][nb][r];
      *(half4*)&g[(nb * 16 + l15) * 64 + ma * 16 + lg * 4] = pk;
    }
}

// ---------------- K2: exclusive prefix scan over chunks ---------------------
__global__ __launch_bounds__(256) void scan_kernel(
    const _Float16* __restrict__ GT, _Float16* __restrict__ ST) {
  const int gid = blockIdx.x * 256 + threadIdx.x;  // 0..131071
  const int bh = gid >> 12, el = gid & 4095;
  const size_t base = (size_t)bh * NCH * 4096 + el;
  float acc = 0.f;
  for (int c = 0; c < NCH; ++c) {
    ST[base + (size_t)c * 4096] = (_Float16)acc;  // exclusive
    acc += (float)GT[base + (size_t)c * 4096];
  }
}

// ---------------- K3: O^T = S^T Q^T + V^T scores^T  (per b,h,chunk) ---------
__global__ __launch_bounds__(64) void attn_chunk_kernel(
    const _Float16* __restrict__ Q, const _Float16* __restrict__ Kb,
    const _Float16* __restrict__ VT, const _Float16* __restrict__ ST,
    _Float16* __restrict__ attn) {
  __shared__ __align__(16) _Float16 sc[64 * 72];  // scores[t][t'], padded
  const int c = blockIdx.x & 31, bh = blockIdx.x >> 5;
  const int b = bh >> 4, h = bh & 15;
  const int lane = threadIdx.x, l15 = lane & 15, lg = lane >> 4;
  const long tok0 = (long)b * TSEQ + c * 64;

  half8 qb[4][2];
#pragma unroll
  for (int nb = 0; nb < 4; ++nb)
#pragma unroll
    for (int ks = 0; ks < 2; ++ks)
      qb[nb][ks] = *(const half8*)&Q[(size_t)(tok0 + nb * 16 + l15) * EE +
                                     h * 64 + ks * 32 + lg * 8];

  f32x4 sT[4][4] = {};
#pragma unroll
  for (int ks = 0; ks < 2; ++ks) {
    half8 kf[4];
#pragma unroll
    for (int ma = 0; ma < 4; ++ma)
      kf[ma] = *(const half8*)&Kb[(size_t)(tok0 + ma * 16 + l15) * EE +
                                  h * 64 + ks * 32 + lg * 8];
#pragma unroll
    for (int ma = 0; ma < 4; ++ma)
#pragma unroll
      for (int nb = 0; nb < 4; ++nb)
        sT[ma][nb] = __builtin_amdgcn_mfma_f32_16x16x32_f16(
            kf[ma], qb[nb][ks], sT[ma][nb], 0, 0, 0);
  }
#pragma unroll
  for (int ma = 0; ma < 4; ++ma)
#pragma unroll
    for (int nb = 0; nb < 4; ++nb) {
      const int tp0 = ma * 16 + lg * 4, t = nb * 16 + l15;
      half4 pk;
#pragma unroll
      for (int r = 0; r < 4; ++r)
        pk[r] = (tp0 + r <= t) ? (_Float16)sT[ma][nb][r] : (_Float16)0.f;
      *(half4*)&sc[t * 72 + tp0] = pk;
    }
  __syncthreads();

  f32x4 o[4][4] = {};
  const _Float16* st = ST + ((size_t)bh * NCH + c) * 4096;
#pragma unroll
  for (int ks = 0; ks < 2; ++ks) {
    half8 sf[4];
#pragma unroll
    for (int ma = 0; ma < 4; ++ma)
      sf[ma] = *(const half8*)&st[(ma * 16 + l15) * 64 + ks * 32 + lg * 8];
#pragma unroll
    for (int ma = 0; ma < 4; ++ma)
#pragma unroll
      for (int nb = 0; nb < 4; ++nb)
        o[ma][nb] = __builtin_amdgcn_mfma_f32_16x16x32_f16(
            sf[ma], qb[nb][ks], o[ma][nb], 0, 0, 0);
  }
#pragma unroll
  for (int ks = 0; ks < 2; ++ks) {
    half8 vf[4], sb[4];
#pragma unroll
    for (int ma = 0; ma < 4; ++ma)
      vf[ma] = *(const half8*)&VT[(size_t)(h * 64 + ma * 16 + l15) * TOK +
                                  tok0 + ks * 32 + lg * 8];
#pragma unroll
    for (int nb = 0; nb < 4; ++nb)
      sb[nb] = *(const half8*)&sc[(nb * 16 + l15) * 72 + ks * 32 + lg * 8];
#pragma unroll
    for (int ma = 0; ma < 4; ++ma)
#pragma unroll
      for (int nb = 0; nb < 4; ++nb)
        o[ma][nb] = __builtin_amdgcn_mfma_f32_16x16x32_f16(
            vf[ma], sb[nb], o[ma][nb], 0, 0, 0);
  }
#pragma unroll
  for (int ma = 0; ma < 4; ++ma)
#pragma unroll
    for (int nb = 0; nb < 4; ++nb) {
      const int t = nb * 16 + l15, d20 = ma * 16 + lg * 4;
      half4 pk;
#pragma unroll
      for (int r = 0; r < 4; ++r) pk[r] = (_Float16)(o[ma][nb][r] * 0.125f);
      *(half4*)&attn[(size_t)(tok0 + t) * EE + h * 64 + d20] = pk;
    }
}

// ---------------------------------------------------------------------------
extern "C" void kernel_launch(void* const* d_in, const int* in_sizes, int n_in,
                              void* d_out, int out_size, void* d_ws,
                              size_t ws_size, hipStream_t stream) {
  const float* q = (const float*)d_in[0];
  const float* k = (const float*)d_in[1];
  const float* v = (const float*)d_in[2];
  const float* Wq = (const float*)d_in[3];
  const float* Wk = (const float*)d_in[4];
  const float* Wv = (const float*)d_in[5];
  const float* in_bias = (const float*)d_in[6];
  const float* Wo = (const float*)d_in[7];
  const float* bo = (const float*)d_in[8];
  float* out = (float*)d_out;

  char* ws = (char*)d_ws;
  const size_t MB = 1u << 20;
  _Float16* wb = (_Float16*)(ws + 0 * MB);
  _Float16* xq = (_Float16*)(ws + 8 * MB);   // xq|xk|xv contiguous 24 MB
  _Float16* xk = (_Float16*)(ws + 16 * MB);
  _Float16* xv = (_Float16*)(ws + 24 * MB);
  _Float16* Qb = (_Float16*)(ws + 32 * MB);
  _Float16* Kbf = (_Float16*)(ws + 40 * MB);
  _Float16* KT = (_Float16*)(ws + 48 * MB);
  _Float16* VT = (_Float16*)(ws + 56 * MB);
  _Float16* attnb = (_Float16*)(ws + 8 * MB);   // reuse XQ
  _Float16* GT = (_Float16*)(ws + 16 * MB);     // reuse XK
  _Float16* STb = (_Float16*)(ws + 24 * MB);    // reuse XV

  pack_x_kernel<<<12288, 256, 0, stream>>>(q, k, v, xq, xk, xv);
  pack_w_kernel<<<4096, 256, 0, stream>>>(Wq, Wk, Wv, Wo, wb);

  gemm_inproj<<<192, 512, 0, stream>>>(xq, wb, in_bias, Qb, Kbf, KT, VT);

  chunk_g_kernel<<<1024, 64, 0, stream>>>(KT, VT, GT);
  scan_kernel<<<512, 256, 0, stream>>>(GT, STb);
  attn_chunk_kernel<<<1024, 64, 0, stream>>>(Qb, Kbf, VT, STb, attnb);

  gemm_out<<<64, 512, 0, stream>>>(wb + 3145728, attnb, bo, out);
}

// Round 7
// 199.863 us; speedup vs baseline: 1.0890x; 1.0890x over previous
//
#include <hip/hip_runtime.h>

// ---------------------------------------------------------------------------
// TrimMultiheadAttention: fused in-proj (x@W^T+b), causal linear attention
// (chunked scan over outer-product state), out-proj, [T,B,E] output.
// All matmuls FP16 MFMA 16x16x32, fp32 accumulate.
// R6/R7: GEMM core rebuilt as BK=32 TRIPLE-buffered pipeline (T3+T4):
//     phase T: stage(T+2) -> buf[(T+2)%3] ; compute buf[T%3] ; vmcnt(4)
//     (T+2's loads stay in flight ACROSS the barrier) ; one s_barrier.
//     128^2 tile, 4 waves, 48KB LDS -> 3 blocks/CU; full-machine grids
//     (in-proj 768, out-proj 256).  R5 postmortem: 2-phase structure was the
//     72% overhead (m233); tile size was not the lever.
//
// Shapes: T=2048, B=2, E=1024, H=16, D=64.  TOK = B*T = 4096.
//
// Workspace layout (bytes), peak 64 MB:
//   [0,8M)    WB   : fp16 weights Wq|Wk|Wv|Wo (1Mi elems each)
//   [8,16M)   XQ   : fp16 [4096][1024] packed query  (later reused as ATTN)
//   [16,24M)  XK   :                  key            (later reused as GT)
//   [24,32M)  XV   :                  value          (later reused as ST)
//   [32,40M)  Q    : fp16 [4096][1024]
//   [40,48M)  K    : fp16 [4096][1024]
//   [48,56M)  KT   : fp16 [1024][4096]  (K transposed)
//   [56,64M)  VT   : fp16 [1024][4096]  (V transposed)
// ---------------------------------------------------------------------------

#define TSEQ 2048
#define BBATCH 2
#define EE 1024
#define TOK 4096
#define NCH 32

typedef _Float16 half8 __attribute__((ext_vector_type(8)));
typedef _Float16 half4 __attribute__((ext_vector_type(4)));
typedef float f32x4 __attribute__((ext_vector_type(4)));

#ifndef __has_builtin
#define __has_builtin(x) 0
#endif
#if __has_builtin(__builtin_amdgcn_global_load_lds)
#define USE_GLL 1
#endif

#ifdef USE_GLL
typedef __attribute__((address_space(1))) const unsigned int guint_t;
typedef __attribute__((address_space(3))) unsigned int luint_t;
#endif

// ---------------- pack kernels: fp32 -> fp16, [T,B,E] -> [b*T+t][E] ----------
__global__ __launch_bounds__(256) void pack_x_kernel(
    const float* __restrict__ q, const float* __restrict__ k,
    const float* __restrict__ v,
    _Float16* __restrict__ xq, _Float16* __restrict__ xk,
    _Float16* __restrict__ xv) {
  const int blk = blockIdx.x;
  const int m = blk >> 12;        // 0=q 1=k 2=v
  const int row = blk & 4095;     // token = b*TSEQ + t
  const int b = row >> 11, t = row & 2047;
  const float* src = (m == 0 ? q : (m == 1 ? k : v)) +
                     (size_t)t * (BBATCH * EE) + (size_t)b * EE;
  _Float16* dst = (m == 0 ? xq : (m == 1 ? xk : xv)) + (size_t)row * EE;
  const int e = threadIdx.x * 4;
  f32x4 f = *(const f32x4*)&src[e];
  half4 h;
  h[0] = (_Float16)f[0]; h[1] = (_Float16)f[1];
  h[2] = (_Float16)f[2]; h[3] = (_Float16)f[3];
  *(half4*)&dst[e] = h;
}

__global__ __launch_bounds__(256) void pack_w_kernel(
    const float* __restrict__ wq, const float* __restrict__ wk,
    const float* __restrict__ wv, const float* __restrict__ wo,
    _Float16* __restrict__ wb) {
  const int blk = blockIdx.x;
  const int m = blk >> 10, row = blk & 1023;
  const float* src =
      (m == 0 ? wq : (m == 1 ? wk : (m == 2 ? wv : wo))) + (size_t)row * EE;
  _Float16* dst = wb + (size_t)m * EE * EE + (size_t)row * EE;
  const int e = threadIdx.x * 4;
  f32x4 f = *(const f32x4*)&src[e];
  half4 h;
  h[0] = (_Float16)f[0]; h[1] = (_Float16)f[1];
  h[2] = (_Float16)f[2]; h[3] = (_Float16)f[3];
  *(half4*)&dst[e] = h;
}

// ---------------- 128x128 GEMM core, BK=32, TRIPLE-buffered -----------------
// LDS tile per buffer: [128 rows][4 slots of 16B]; elem (r,s) stored at slot
// s ^ ((r>>1)&3) (involution; 2-way max bank aliasing on ds_read_b128).
// Stage keeps LDS dest LINEAR (global_load_lds rule) and swizzles the global
// SOURCE column (both-sides-or-neither, rule #21).
__device__ __forceinline__ void stage32(
    const _Float16* __restrict__ A, const _Float16* __restrict__ Bm,
    long arow0, long brow0, int k0, int tid, int w,
    _Float16* __restrict__ Ab, _Float16* __restrict__ Bb) {
#pragma unroll
  for (int rnd = 0; rnd < 2; ++rnd) {
    const int flat = rnd * 256 + tid;  // 16B units, 0..511
    const int r = flat >> 2, s = flat & 3;
    const int c = (s ^ ((r >> 1) & 3)) * 8;  // swizzled source col (elems)
    const _Float16* ga = &A[(size_t)(arow0 + r) * 1024 + k0 + c];
    const _Float16* gb = &Bm[(size_t)(brow0 + r) * 1024 + k0 + c];
#ifdef USE_GLL
    const int ubase = (rnd * 256 + w * 64) * 8;  // wave-uniform elem offset
    __builtin_amdgcn_global_load_lds((guint_t*)ga, (luint_t*)&Ab[ubase], 16, 0,
                                     0);
    __builtin_amdgcn_global_load_lds((guint_t*)gb, (luint_t*)&Bb[ubase], 16, 0,
                                     0);
#else
    *(half8*)&Ab[flat * 8] = *(const half8*)ga;
    *(half8*)&Bb[flat * 8] = *(const half8*)gb;
#endif
  }
}

// 4 waves as 2(M) x 2(N); per-wave output 64x64 = acc[4][4] fragments.
// Phase T: stage(T+2)->buf[(T+2)%3]; read+MFMA buf[T%3]; vmcnt(4); barrier.
// Race-freedom: buffers {read T%3, staged (T+2)%3, in-flight (T+1)%3} are
// pairwise distinct mod 3; stage of X issues after barrier ending X-3's
// compute; vmcnt(4)+barrier at end of T-1 guarantees tile T landed.
__device__ __forceinline__ void gemm_core32(
    const _Float16* __restrict__ A, const _Float16* __restrict__ Bm,
    long arow0, long brow0, int tid, f32x4 (&acc)[4][4],
    _Float16 (&Ab)[3][4096], _Float16 (&Bb)[3][4096]) {
  const int lane = tid & 63, w = tid >> 6;
  const int wr = w >> 1, wc = w & 1;
  const int l15 = lane & 15, lg = lane >> 4;
  const int slotx = (l15 >> 1) & 3;  // read-side swizzle ((row>>1)&3)

#ifdef USE_GLL
  // prologue: tiles 0 and 1 staged; vmcnt(4) -> tile 0 landed, tile 1 flying.
  stage32(A, Bm, arow0, brow0, 0, tid, w, Ab[0], Bb[0]);
  stage32(A, Bm, arow0, brow0, 32, tid, w, Ab[1], Bb[1]);
  asm volatile("s_waitcnt vmcnt(4)" ::: "memory");
  __builtin_amdgcn_s_barrier();
  int cur = 0, nxt2 = 2;
  for (int T = 0; T < 32; ++T) {
    __builtin_amdgcn_sched_barrier(0);  // pin phase body below the barrier
    if (T + 2 < 32)
      stage32(A, Bm, arow0, brow0, (T + 2) * 32, tid, w, Ab[nxt2], Bb[nxt2]);
    half8 af[4], bf[4];
#pragma unroll
    for (int mi = 0; mi < 4; ++mi)
      af[mi] = *(const half8*)&Ab[cur][(wr * 64 + mi * 16 + l15) * 32 +
                                       ((lg ^ slotx) * 8)];
#pragma unroll
    for (int ni = 0; ni < 4; ++ni)
      bf[ni] = *(const half8*)&Bb[cur][(wc * 64 + ni * 16 + l15) * 32 +
                                       ((lg ^ slotx) * 8)];
#pragma unroll
    for (int mi = 0; mi < 4; ++mi)
#pragma unroll
      for (int ni = 0; ni < 4; ++ni)
        acc[mi][ni] = __builtin_amdgcn_mfma_f32_16x16x32_f16(
            af[mi], bf[ni], acc[mi][ni], 0, 0, 0);
    __builtin_amdgcn_sched_barrier(0);  // nothing sinks past the barrier
    if (T < 30) {
      asm volatile("s_waitcnt vmcnt(4)" ::: "memory");  // tile T+1 landed
    } else if (T == 30) {
      asm volatile("s_waitcnt vmcnt(0)" ::: "memory");  // drain for tile 31
    }
    if (T < 31) __builtin_amdgcn_s_barrier();
    cur = (cur == 2) ? 0 : cur + 1;
    nxt2 = (nxt2 == 2) ? 0 : nxt2 + 1;
  }
#else
  for (int T = 0; T < 32; ++T) {
    __syncthreads();
    stage32(A, Bm, arow0, brow0, T * 32, tid, w, Ab[0], Bb[0]);
    __syncthreads();
    half8 af[4], bf[4];
#pragma unroll
    for (int mi = 0; mi < 4; ++mi)
      af[mi] = *(const half8*)&Ab[0][(wr * 64 + mi * 16 + l15) * 32 +
                                     ((lg ^ slotx) * 8)];
#pragma unroll
    for (int ni = 0; ni < 4; ++ni)
      bf[ni] = *(const half8*)&Bb[0][(wc * 64 + ni * 16 + l15) * 32 +
                                     ((lg ^ slotx) * 8)];
#pragma unroll
    for (int mi = 0; mi < 4; ++mi)
#pragma unroll
      for (int ni = 0; ni < 4; ++ni)
        acc[mi][ni] = __builtin_amdgcn_mfma_f32_16x16x32_f16(
            af[mi], bf[ni], acc[mi][ni], 0, 0, 0);
  }
#endif
}

// ---------------- merged in-projection GEMM (768 blocks, XCD-chunked) -------
// Logical grid: 32 m-blocks (tokens) x 24 cols (3 sections x 8 n-blocks).
// HW bid round-robins XCDs: logical = (bid&7)*96 + bid>>3 -> each XCD owns a
// 4(m) x 24(col) rectangle (A-band 1MB L2-resident, B streams).
__global__ __launch_bounds__(256, 3) void gemm_inproj(
    const _Float16* __restrict__ X, const _Float16* __restrict__ WB,
    const float* __restrict__ bias, _Float16* __restrict__ Qb,
    _Float16* __restrict__ Kbf, _Float16* __restrict__ KT,
    _Float16* __restrict__ VT) {
  __shared__ __align__(16) _Float16 Ab[3][4096];
  __shared__ __align__(16) _Float16 Bb[3][4096];
  const int tid = threadIdx.x;
  const int logical = (blockIdx.x & 7) * 96 + (blockIdx.x >> 3);
  const int mb = logical / 24;               // 0..31 (token block)
  const int col = logical % 24;              // 0..23
  const int which = col >> 3, nb = col & 7;  // section, n-block
  const long arow0 = (long)mb * 128;         // token
  const long brow0 = (long)nb * 128;         // e within section
  const _Float16* A = X + (size_t)which * (TOK * EE);
  const _Float16* Bm = WB + (size_t)which * (EE * EE);
  const float* bs = bias + which * EE;

  f32x4 acc[4][4] = {};
  gemm_core32(A, Bm, arow0, brow0, tid, acc, Ab, Bb);

  const int lane = tid & 63, w = tid >> 6;
  const int wr = w >> 1, wc = w & 1;
  const int l15 = lane & 15, lg = lane >> 4;
#pragma unroll
  for (int mi = 0; mi < 4; ++mi) {
#pragma unroll
    for (int ni = 0; ni < 4; ++ni) {
      const long gm = arow0 + wr * 64 + mi * 16 + lg * 4;  // token (+r)
      const long gn = brow0 + wc * 64 + ni * 16 + l15;     // e in section
      const float bv = bs[gn];
      float vv[4];
#pragma unroll
      for (int r = 0; r < 4; ++r) vv[r] = acc[mi][ni][r] + bv;
      if (which == 0) {
#pragma unroll
        for (int r = 0; r < 4; ++r)
          Qb[(size_t)(gm + r) * EE + gn] = (_Float16)vv[r];
      } else if (which == 1) {
#pragma unroll
        for (int r = 0; r < 4; ++r)
          Kbf[(size_t)(gm + r) * EE + gn] = (_Float16)vv[r];
        half4 pk;
#pragma unroll
        for (int r = 0; r < 4; ++r) pk[r] = (_Float16)vv[r];
        *(half4*)&KT[(size_t)gn * TOK + gm] = pk;
      } else {
        half4 pk;
#pragma unroll
        for (int r = 0; r < 4; ++r) pk[r] = (_Float16)vv[r];
        *(half4*)&VT[(size_t)gn * TOK + gm] = pk;
      }
    }
  }
}

// ---------------- out projection (256 blocks, XCD-chunked) ------------------
// OF[t][b][eo] = Wo[eo][:] . attn[tok][:] + bo[eo].  8 m-blocks x 32 cols.
__global__ __launch_bounds__(256, 3) void gemm_out(
    const _Float16* __restrict__ Wo, const _Float16* __restrict__ ATT,
    const float* __restrict__ bo, float* __restrict__ OF) {
  __shared__ __align__(16) _Float16 Ab[3][4096];
  __shared__ __align__(16) _Float16 Bb[3][4096];
  const int tid = threadIdx.x;
  const int logical = (blockIdx.x & 7) * 32 + (blockIdx.x >> 3);
  const int mb = logical >> 5;   // 0..7  (eo block)
  const int col = logical & 31;  // 0..31 (token block)
  const long arow0 = (long)mb * 128;
  const long brow0 = (long)col * 128;

  f32x4 acc[4][4] = {};
  gemm_core32(Wo, ATT, arow0, brow0, tid, acc, Ab, Bb);

  const int lane = tid & 63, w = tid >> 6;
  const int wr = w >> 1, wc = w & 1;
  const int l15 = lane & 15, lg = lane >> 4;
#pragma unroll
  for (int mi = 0; mi < 4; ++mi) {
#pragma unroll
    for (int ni = 0; ni < 4; ++ni) {
      const long gm = arow0 + wr * 64 + mi * 16 + lg * 4;  // eo (+r)
      const long gn = brow0 + wc * 64 + ni * 16 + l15;     // token
      const int t = (int)(gn & 2047), b2 = (int)(gn >> 11);
      f32x4 res;
#pragma unroll
      for (int r = 0; r < 4; ++r) res[r] = acc[mi][ni][r] + bo[gm + r];
      *(f32x4*)&OF[(size_t)t * (BBATCH * EE) + (size_t)b2 * EE + gm] = res;
    }
  }
}

// ---------------- K1: per-chunk G^T = (K_c^T V_c)^T stored [d2][d1] ---------
__global__ __launch_bounds__(64) void chunk_g_kernel(
    const _Float16* __restrict__ KT, const _Float16* __restrict__ VT,
    _Float16* __restrict__ GT) {
  const int c = blockIdx.x & 31, bh = blockIdx.x >> 5;
  const int b = bh >> 4, h = bh & 15;
  const int lane = threadIdx.x, l15 = lane & 15, lg = lane >> 4;
  const long tok0 = (long)b * TSEQ + c * 64;

  half8 af[4][2], bf[4][2];
#pragma unroll
  for (int ma = 0; ma < 4; ++ma)
#pragma unroll
    for (int ks = 0; ks < 2; ++ks) {
      const size_t rowoff = (size_t)(h * 64 + ma * 16 + l15) * TOK + tok0 +
                            ks * 32 + lg * 8;
      af[ma][ks] = *(const half8*)&KT[rowoff];
      bf[ma][ks] = *(const half8*)&VT[rowoff];
    }
  f32x4 acc[4][4] = {};
#pragma unroll
  for (int ks = 0; ks < 2; ++ks)
#pragma unroll
    for (int ma = 0; ma < 4; ++ma)
#pragma unroll
      for (int nb = 0; nb < 4; ++nb)
        acc[ma][nb] = __builtin_amdgcn_mfma_f32_16x16x32_f16(
            af[ma][ks], bf[nb][ks], acc[ma][nb], 0, 0, 0);
  _Float16* g = GT + ((size_t)bh * NCH + c) * 4096;
#pragma unroll
  for (int ma = 0; ma < 4; ++ma)
#pragma unroll
    for (int nb = 0; nb < 4; ++nb) {
      half4 pk;
#pragma unroll
      for (int r = 0; r < 4; ++r) pk[r] = (_Float16)acc[ma][nb][r];
      *(half4*)&g[(nb * 16 + l15) * 64 + ma * 16 + lg * 4] = pk;
    }
}

// ---------------- K2: exclusive prefix scan over chunks ---------------------
__global__ __launch_bounds__(256) void scan_kernel(
    const _Float16* __restrict__ GT, _Float16* __restrict__ ST) {
  const int gid = blockIdx.x * 256 + threadIdx.x;  // 0..131071
  const int bh = gid >> 12, el = gid & 4095;
  const size_t base = (size_t)bh * NCH * 4096 + el;
  float acc = 0.f;
  for (int c = 0; c < NCH; ++c) {
    ST[base + (size_t)c * 4096] = (_Float16)acc;  // exclusive
    acc += (float)GT[base + (size_t)c * 4096];
  }
}

// ---------------- K3: O^T = S^T Q^T + V^T scores^T  (per b,h,chunk) ---------
__global__ __launch_bounds__(64) void attn_chunk_kernel(
    const _Float16* __restrict__ Q, const _Float16* __restrict__ Kb,
    const _Float16* __restrict__ VT, const _Float16* __restrict__ ST,
    _Float16* __restrict__ attn) {
  __shared__ __align__(16) _Float16 sc[64 * 72];  // scores[t][t'], padded
  const int c = blockIdx.x & 31, bh = blockIdx.x >> 5;
  const int b = bh >> 4, h = bh & 15;
  const int lane = threadIdx.x, l15 = lane & 15, lg = lane >> 4;
  const long tok0 = (long)b * TSEQ + c * 64;

  half8 qb[4][2];
#pragma unroll
  for (int nb = 0; nb < 4; ++nb)
#pragma unroll
    for (int ks = 0; ks < 2; ++ks)
      qb[nb][ks] = *(const half8*)&Q[(size_t)(tok0 + nb * 16 + l15) * EE +
                                     h * 64 + ks * 32 + lg * 8];

  f32x4 sT[4][4] = {};
#pragma unroll
  for (int ks = 0; ks < 2; ++ks) {
    half8 kf[4];
#pragma unroll
    for (int ma = 0; ma < 4; ++ma)
      kf[ma] = *(const half8*)&Kb[(size_t)(tok0 + ma * 16 + l15) * EE +
                                  h * 64 + ks * 32 + lg * 8];
#pragma unroll
    for (int ma = 0; ma < 4; ++ma)
#pragma unroll
      for (int nb = 0; nb < 4; ++nb)
        sT[ma][nb] = __builtin_amdgcn_mfma_f32_16x16x32_f16(
            kf[ma], qb[nb][ks], sT[ma][nb], 0, 0, 0);
  }
#pragma unroll
  for (int ma = 0; ma < 4; ++ma)
#pragma unroll
    for (int nb = 0; nb < 4; ++nb) {
      const int tp0 = ma * 16 + lg * 4, t = nb * 16 + l15;
      half4 pk;
#pragma unroll
      for (int r = 0; r < 4; ++r)
        pk[r] = (tp0 + r <= t) ? (_Float16)sT[ma][nb][r] : (_Float16)0.f;
      *(half4*)&sc[t * 72 + tp0] = pk;
    }
  __syncthreads();

  f32x4 o[4][4] = {};
  const _Float16* st = ST + ((size_t)bh * NCH + c) * 4096;
#pragma unroll
  for (int ks = 0; ks < 2; ++ks) {
    half8 sf[4];
#pragma unroll
    for (int ma = 0; ma < 4; ++ma)
      sf[ma] = *(const half8*)&st[(ma * 16 + l15) * 64 + ks * 32 + lg * 8];
#pragma unroll
    for (int ma = 0; ma < 4; ++ma)
#pragma unroll
      for (int nb = 0; nb < 4; ++nb)
        o[ma][nb] = __builtin_amdgcn_mfma_f32_16x16x32_f16(
            sf[ma], qb[nb][ks], o[ma][nb], 0, 0, 0);
  }
#pragma unroll
  for (int ks = 0; ks < 2; ++ks) {
    half8 vf[4], sb[4];
#pragma unroll
    for (int ma = 0; ma < 4; ++ma)
      vf[ma] = *(const half8*)&VT[(size_t)(h * 64 + ma * 16 + l15) * TOK +
                                  tok0 + ks * 32 + lg * 8];
#pragma unroll
    for (int nb = 0; nb < 4; ++nb)
      sb[nb] = *(const half8*)&sc[(nb * 16 + l15) * 72 + ks * 32 + lg * 8];
#pragma unroll
    for (int ma = 0; ma < 4; ++ma)
#pragma unroll
      for (int nb = 0; nb < 4; ++nb)
        o[ma][nb] = __builtin_amdgcn_mfma_f32_16x16x32_f16(
            vf[ma], sb[nb], o[ma][nb], 0, 0, 0);
  }
#pragma unroll
  for (int ma = 0; ma < 4; ++ma)
#pragma unroll
    for (int nb = 0; nb < 4; ++nb) {
      const int t = nb * 16 + l15, d20 = ma * 16 + lg * 4;
      half4 pk;
#pragma unroll
      for (int r = 0; r < 4; ++r) pk[r] = (_Float16)(o[ma][nb][r] * 0.125f);
      *(half4*)&attn[(size_t)(tok0 + t) * EE + h * 64 + d20] = pk;
    }
}

// ---------------------------------------------------------------------------
extern "C" void kernel_launch(void* const* d_in, const int* in_sizes, int n_in,
                              void* d_out, int out_size, void* d_ws,
                              size_t ws_size, hipStream_t stream) {
  const float* q = (const float*)d_in[0];
  const float* k = (const float*)d_in[1];
  const float* v = (const float*)d_in[2];
  const float* Wq = (const float*)d_in[3];
  const float* Wk = (const float*)d_in[4];
  const float* Wv = (const float*)d_in[5];
  const float* in_bias = (const float*)d_in[6];
  const float* Wo = (const float*)d_in[7];
  const float* bo = (const float*)d_in[8];
  float* out = (float*)d_out;

  char* ws = (char*)d_ws;
  const size_t MB = 1u << 20;
  _Float16* wb = (_Float16*)(ws + 0 * MB);
  _Float16* xq = (_Float16*)(ws + 8 * MB);   // xq|xk|xv contiguous 24 MB
  _Float16* xk = (_Float16*)(ws + 16 * MB);
  _Float16* xv = (_Float16*)(ws + 24 * MB);
  _Float16* Qb = (_Float16*)(ws + 32 * MB);
  _Float16* Kbf = (_Float16*)(ws + 40 * MB);
  _Float16* KT = (_Float16*)(ws + 48 * MB);
  _Float16* VT = (_Float16*)(ws + 56 * MB);
  _Float16* attnb = (_Float16*)(ws + 8 * MB);   // reuse XQ
  _Float16* GT = (_Float16*)(ws + 16 * MB);     // reuse XK
  _Float16* STb = (_Float16*)(ws + 24 * MB);    // reuse XV

  pack_x_kernel<<<12288, 256, 0, stream>>>(q, k, v, xq, xk, xv);
  pack_w_kernel<<<4096, 256, 0, stream>>>(Wq, Wk, Wv, Wo, wb);

  gemm_inproj<<<768, 256, 0, stream>>>(xq, wb, in_bias, Qb, Kbf, KT, VT);

  chunk_g_kernel<<<1024, 64, 0, stream>>>(KT, VT, GT);
  scan_kernel<<<512, 256, 0, stream>>>(GT, STb);
  attn_chunk_kernel<<<1024, 64, 0, stream>>>(Qb, Kbf, VT, STb, attnb);

  gemm_out<<<256, 256, 0, stream>>>(wb + 3145728, attnb, bo, out);
}